// Round 14
// baseline (164.416 us; speedup 1.0000x reference)
//
#include <hip/hip_runtime.h>

#define SS 2048
#define NH 16
#define NKV 4
#define HD 64

typedef __bf16 bf16;
typedef __bf16 bf16x4 __attribute__((ext_vector_type(4)));
typedef __bf16 bf16x8 __attribute__((ext_vector_type(8)));
typedef float f32x4 __attribute__((ext_vector_type(4)));

// softmax scale folded into Q at the QKV epilogue: (1/sqrt(64)) * log2(e)
#define SM_SCALE 0.18033688011f

__device__ __forceinline__ void gl_lds16(const bf16* g, bf16* l) {
    __builtin_amdgcn_global_load_lds((const __attribute__((address_space(1))) void*)g,
                                     (__attribute__((address_space(3))) void*)l, 16, 0, 0);
}

// ---------------- prep: transpose/convert weights + convert x to bf16 ----------------
__global__ __launch_bounds__(256) void prep_kernel(
    const float* __restrict__ x,
    const float* __restrict__ Wq, const float* __restrict__ Wk,
    const float* __restrict__ Wv, const float* __restrict__ Wo,
    bf16* __restrict__ wqkv_t, bf16* __restrict__ wo_t, bf16* __restrict__ xb)
{
    const int blk = blockIdx.x;
    const int tid = threadIdx.x;
    if (blk >= 640) {
        const size_t i0 = (size_t)(blk - 640) * 16384;
        #pragma unroll
        for (int i = 0; i < 16; ++i) {
            const size_t idx = i0 + i * 1024 + tid * 4;
            const float4 v = *(const float4*)&x[idx];
            bf16x4 o4;
            o4[0] = (bf16)v.x; o4[1] = (bf16)v.y; o4[2] = (bf16)v.z; o4[3] = (bf16)v.w;
            *(bf16x4*)&xb[idx] = o4;
        }
        return;
    }
    const float* W; bf16* Wt; int N, n0, k0;
    if (blk < 256)      { W = Wq; Wt = wqkv_t;                       N = 1024; n0 = (blk & 15) * 64;         k0 = (blk >> 4) * 64; }
    else if (blk < 320) { W = Wk; Wt = wqkv_t + (size_t)1024 * 1024; N = 256;  n0 = ((blk - 256) & 3) * 64;  k0 = ((blk - 256) >> 2) * 64; }
    else if (blk < 384) { W = Wv; Wt = wqkv_t + (size_t)1280 * 1024; N = 256;  n0 = ((blk - 320) & 3) * 64;  k0 = ((blk - 320) >> 2) * 64; }
    else                { W = Wo; Wt = wo_t;                         N = 1024; n0 = ((blk - 384) & 15) * 64; k0 = ((blk - 384) >> 4) * 64; }

    __shared__ float Ts[64][65];
    const int c = tid & 63, rr = tid >> 6;
    #pragma unroll
    for (int i = 0; i < 16; ++i) {
        const int kk = i * 4 + rr;
        Ts[kk][c] = W[(size_t)(k0 + kk) * N + n0 + c];
    }
    __syncthreads();
    #pragma unroll
    for (int i = 0; i < 16; ++i) {
        const int nn = i * 4 + rr;
        Wt[(size_t)(n0 + nn) * 1024 + k0 + c] = (bf16)Ts[c][nn];
    }
}

// ---------------- QKV GEMM: 64x128 tile, BK=32, NBUF=3, single barrier per K-step ----------
// Round-14: BK shrink changes SCHEDULE GRANULARITY ONLY (staged bytes/output-elem are
// tile-MxN-determined: still 48B — round-10's regression mechanism does not apply).
// LDS = 3 x (64x32 + 128x32) x 2B = 36 KB -> 4 blocks/CU (was 3 at BK=64 2-buf 48 KB).
// Single-barrier 3-buf schedule (round-8/9-verified on O-GEMM), now affordable at 4/CU:
//   iter t: s_waitcnt vmcnt(3); s_barrier; issue stage(t+2)->buf[(t+2)%3]; 8 MFMA.
// Barrier count unchanged (32x1 vs 16x2); prefetch distance unchanged (2 tiles ahead).
// BK=32 swizzle (re-derived): 4 chunks of 8 elems per row; store pre-swizzled global
// chunk (tid&3)^((srow>>1)&3); read phys (g^((li>>1)&3))*8. Bank algebra: 16 lanes hit
// {g,4+g,g^1,4+g^1,g^2,4+g^2,g^3,4+g^3} bank-groups x2 = 2-way (free, m136); the row>>1
// form is store/read-consistent since all wave-row offsets are multiples of 16.
// Fused RoPE + QKV split epilogue (identical to BK=64 version), Q pre-scaled, packed V^T.
__global__ __launch_bounds__(256) void gemm_qkv32_kernel(
    const bf16* __restrict__ A, const bf16* __restrict__ Bt,
    const float* __restrict__ cosp, const float* __restrict__ sinp,
    bf16* __restrict__ qo, bf16* __restrict__ ko, bf16* __restrict__ vto,
    int N, int K, int CB)
{
    __shared__ bf16 As[3][64 * 32];    // 3 x 4 KB
    __shared__ bf16 Bs[3][128 * 32];   // 3 x 8 KB -> 36 KB total, 4 blocks/CU
    const int bid = blockIdx.x;
    const int j = bid >> 3;
    const int rb = (bid & 7) + 8 * (j / CB);
    const int cb = j % CB;
    const int m0 = rb * 64, n0 = cb * 128;
    const int tid = threadIdx.x;
    const int w = tid >> 6, lane = tid & 63, g = lane >> 4, li = lane & 15;
    const int wm = w >> 1, wn = w & 1;  // wave tile: rows wm*32+mi*16 (mi<2), cols wn*64+ni*16 (ni<4)

    f32x4 acc[2][4];
    const f32x4 z = {0.f, 0.f, 0.f, 0.f};
    #pragma unroll
    for (int i = 0; i < 2; ++i)
        #pragma unroll
        for (int jj = 0; jj < 4; ++jj) acc[i][jj] = z;

    // staging sweep = 256 thr x 16B = 64 rows x 32 elems; A: 1 sweep, B: 2 sweeps.
    const int srow = tid >> 2;                                   // 0..63 (row within sweep)
    const int schunk = ((tid & 3) ^ ((srow >> 1) & 3)) * 8;      // pre-swizzled global chunk
    const bf16* pA = A + (size_t)(m0 + srow) * K + schunk;
    const bf16* pB[2];
    #pragma unroll
    for (int s = 0; s < 2; ++s) pB[s] = Bt + (size_t)(n0 + s * 64 + srow) * K + schunk;
    const int lw = w * 512;   // wave-uniform LDS offset (wave covers 16 rows x 32 elems)

    const int NT = K >> 5;    // 32 K-steps

    // ---- prologue: stage tiles 0 and 1 into buf 0 and 1 (3 gl_lds per thread per tile) ----
    gl_lds16(pA, &As[0][lw]);
    #pragma unroll
    for (int s = 0; s < 2; ++s) gl_lds16(pB[s], &Bs[0][s * 2048 + lw]);
    gl_lds16(pA + 32, &As[1][lw]);
    #pragma unroll
    for (int s = 0; s < 2; ++s) gl_lds16(pB[s] + 32, &Bs[1][s * 2048 + lw]);

    int cur = 0;
    for (int t = 0; t < NT; ++t) {
        // wait for stage(t) only; stage(t+1)'s 3 loads stay in flight across the barrier
        if (t + 1 < NT) { asm volatile("s_waitcnt vmcnt(3)" ::: "memory"); }
        else            { asm volatile("s_waitcnt vmcnt(0)" ::: "memory"); }
        __builtin_amdgcn_s_barrier();
        // issue next+1 staging into the buffer whose reads finished at iter t-1
        if (t + 2 < NT) {
            const int kk = (t + 2) << 5;
            const int nb = (cur + 2 >= 3) ? cur - 1 : cur + 2;   // (cur+2)%3
            gl_lds16(pA + kk, &As[nb][lw]);
            #pragma unroll
            for (int s = 0; s < 2; ++s) gl_lds16(pB[s] + kk, &Bs[nb][s * 2048 + lw]);
        }
        // compute current tile: one MFMA K-pass (K=32 == one 16x16x32 MFMA depth)
        {
            const int phys = (g ^ ((li >> 1) & 3)) * 8;
            bf16x8 af[2], bfr[4];
            #pragma unroll
            for (int mi = 0; mi < 2; ++mi) af[mi] = *(const bf16x8*)&As[cur][(wm * 32 + mi * 16 + li) * 32 + phys];
            #pragma unroll
            for (int ni = 0; ni < 4; ++ni) bfr[ni] = *(const bf16x8*)&Bs[cur][(wn * 64 + ni * 16 + li) * 32 + phys];
            __builtin_amdgcn_s_setprio(1);
            #pragma unroll
            for (int mi = 0; mi < 2; ++mi)
                #pragma unroll
                for (int ni = 0; ni < 4; ++ni)
                    acc[mi][ni] = __builtin_amdgcn_mfma_f32_16x16x32_bf16(af[mi], bfr[ni], acc[mi][ni], 0, 0, 0);
            __builtin_amdgcn_s_setprio(0);
        }
        cur = (cur + 1 == 3) ? 0 : cur + 1;
    }

    // fused RoPE + split. cols: [0,1024) q (pre-scaled), [1024,1280) k, [1280,1536) v.
    // rotate_half partner of col is col^32 == acc[mi][ni^2][r] (same wave, in-register).
    const int row0 = m0 + wm * 32, col0 = n0 + wn * 64;
    #pragma unroll
    for (int ni = 0; ni < 4; ++ni) {
        const int col = col0 + ni * 16 + li;
        const int d = col & 63;
        #pragma unroll
        for (int mi = 0; mi < 2; ++mi) {
            const int rowb = row0 + mi * 16 + g * 4;       // 4-aligned, never crosses b
            const int bb = rowb >> 11, s0 = rowb & 2047;
            if (col < 1280) {
                #pragma unroll
                for (int r = 0; r < 4; ++r) {
                    const int s = s0 + r;
                    float val = acc[mi][ni][r];
                    const float pairv = acc[mi][ni ^ 2][r];
                    const float rot = (d < 32) ? -pairv : pairv;
                    val = val * cosp[s * 64 + d] + rot * sinp[s * 64 + d];
                    if (col < 1024) {
                        const int hh = col >> 6;
                        qo[(((size_t)bb * NH + hh) * SS + s) * HD + d] = (bf16)(val * SM_SCALE);
                    } else {
                        const int kh = (col - 1024) >> 6;
                        ko[(((size_t)bb * NKV + kh) * SS + s) * HD + d] = (bf16)val;
                    }
                }
            } else {
                // V^T [d][s]: the 4 r-values are s-contiguous -> one 8B packed store
                const int kh = (col - 1280) >> 6;
                bf16x4 p4;
                #pragma unroll
                for (int r = 0; r < 4; ++r) p4[r] = (bf16)acc[mi][ni][r];
                *(bf16x4*)&vto[(((size_t)bb * NKV + kh) * HD + d) * SS + s0] = p4;
            }
        }
    }
}

// ---------------- O GEMM: 64x128 tile, BK=64, NBUF=3 single-barrier (round-9 best) --------
// Grid 512 caps residency at 2 blocks/CU regardless, so the 72 KB 3-buf schedule is free:
//   iter t: s_waitcnt vmcnt(6); s_barrier; issue stage(t+2)->buf[(t+2)%3]; compute.
// Unpadded LDS, chunk-XOR swizzle; XCD-locality mapping (rb spans within XCD).
__global__ __launch_bounds__(256) void gemm_o_kernel(
    const bf16* __restrict__ A, const bf16* __restrict__ Bt, float* __restrict__ C,
    int N, int K, int CB)
{
    __shared__ bf16 As[3][64 * 64];    // 3 x  8 KB
    __shared__ bf16 Bs[3][128 * 64];   // 3 x 16 KB -> 72 KB total
    const int bid = blockIdx.x;
    const int j = bid >> 3;
    const int rb = (bid & 7) + 8 * (j / CB);
    const int cb = j % CB;
    const int m0 = rb * 64, n0 = cb * 128;
    const int tid = threadIdx.x;
    const int w = tid >> 6, lane = tid & 63, g = lane >> 4, li = lane & 15;
    const int wm = w >> 1, wn = w & 1;  // wave tile: rows wm*32+mi*16 (mi<2), cols wn*64+ni*16 (ni<4)

    f32x4 acc[2][4];
    const f32x4 z = {0.f, 0.f, 0.f, 0.f};
    #pragma unroll
    for (int i = 0; i < 2; ++i)
        #pragma unroll
        for (int jj = 0; jj < 4; ++jj) acc[i][jj] = z;

    // staging sweep = 256 thr x 16B = 32 rows x 64 elems; A: 2 sweeps, B: 4 sweeps.
    const int srow = tid >> 3;                          // 0..31 (row within sweep)
    const int schunk = ((tid & 7) ^ (srow & 7)) * 8;    // pre-swizzled global chunk
    const bf16* pA[2];
    const bf16* pB[4];
    #pragma unroll
    for (int s = 0; s < 2; ++s) pA[s] = A + (size_t)(m0 + s * 32 + srow) * K + schunk;
    #pragma unroll
    for (int s = 0; s < 4; ++s) pB[s] = Bt + (size_t)(n0 + s * 32 + srow) * K + schunk;
    const int lw = w * 512;   // wave-uniform LDS offset within each 2048-elem sweep region

    const int NT = K >> 6;    // 16 K-steps

    // ---- prologue: stage tiles 0 and 1 into buf 0 and 1 (6 gl_lds per thread per tile) ----
    #pragma unroll
    for (int s = 0; s < 2; ++s) gl_lds16(pA[s], &As[0][s * 2048 + lw]);
    #pragma unroll
    for (int s = 0; s < 4; ++s) gl_lds16(pB[s], &Bs[0][s * 2048 + lw]);
    #pragma unroll
    for (int s = 0; s < 2; ++s) gl_lds16(pA[s] + 64, &As[1][s * 2048 + lw]);
    #pragma unroll
    for (int s = 0; s < 4; ++s) gl_lds16(pB[s] + 64, &Bs[1][s * 2048 + lw]);

    int cur = 0;
    for (int t = 0; t < NT; ++t) {
        if (t + 1 < NT) { asm volatile("s_waitcnt vmcnt(6)" ::: "memory"); }
        else            { asm volatile("s_waitcnt vmcnt(0)" ::: "memory"); }
        __builtin_amdgcn_s_barrier();
        // issue next+1 staging into the buffer whose reads finished at iter t-1
        if (t + 2 < NT) {
            const int kk = (t + 2) << 6;
            const int nb = (cur + 2 >= 3) ? cur - 1 : cur + 2;   // (cur+2)%3
            #pragma unroll
            for (int s = 0; s < 2; ++s) gl_lds16(pA[s] + kk, &As[nb][s * 2048 + lw]);
            #pragma unroll
            for (int s = 0; s < 4; ++s) gl_lds16(pB[s] + kk, &Bs[nb][s * 2048 + lw]);
        }
        #pragma unroll
        for (int tt = 0; tt < 2; ++tt) {
            const int phys = ((tt * 4 + g) ^ (li & 7)) * 8;
            bf16x8 af[2], bfr[4];
            #pragma unroll
            for (int mi = 0; mi < 2; ++mi) af[mi] = *(const bf16x8*)&As[cur][(wm * 32 + mi * 16 + li) * 64 + phys];
            #pragma unroll
            for (int ni = 0; ni < 4; ++ni) bfr[ni] = *(const bf16x8*)&Bs[cur][(wn * 64 + ni * 16 + li) * 64 + phys];
            __builtin_amdgcn_s_setprio(1);
            #pragma unroll
            for (int mi = 0; mi < 2; ++mi)
                #pragma unroll
                for (int ni = 0; ni < 4; ++ni)
                    acc[mi][ni] = __builtin_amdgcn_mfma_f32_16x16x32_bf16(af[mi], bfr[ni], acc[mi][ni], 0, 0, 0);
            __builtin_amdgcn_s_setprio(0);
        }
        cur = (cur + 1 == 3) ? 0 : cur + 1;
    }

    const int row0 = m0 + wm * 32, col0 = n0 + wn * 64;
    #pragma unroll
    for (int mi = 0; mi < 2; ++mi)
        #pragma unroll
        for (int ni = 0; ni < 4; ++ni)
            #pragma unroll
            for (int r = 0; r < 4; ++r)
                C[(size_t)(row0 + mi * 16 + g * 4 + r) * N + col0 + ni * 16 + li] = acc[mi][ni][r];
}

// ---------------- Flash attention v12 (best measured): v9 loop + balanced qt permutation ----
// 1024 blocks x 256 thr, 4 blocks/CU all resident from t=0. Per-CU-balanced qt mapping
// (t = 8a+b): a=0: qt=b; a=1: qt=31-b; a=2: qt=8+b; a=3: qt=23-b — co-resident sets sum
// to 62 (uniform 66 tiles/CU). Structure ledger: QBLK=128 8-wave (r5,r7) and split-KV
// (r12) all regressed — v9's 4 small independent blocks/CU is the local optimum; kernel
// is VALU+MFMA co-bound (54% VALU + 17% MFMA overlapped across waves).
// Inner loop: counted-vmcnt dbuf KVBLK=64, swapped QK^T (lane holds
// S[key=nt*16+g*4+r][q=li]), packed bf16x4 P writes, chunk-XOR swizzled LDS.
__global__ __launch_bounds__(256) void flash_kernel(const bf16* __restrict__ q, const bf16* __restrict__ k,
                                                    const bf16* __restrict__ vt, bf16* __restrict__ o)
{
    __shared__ bf16 Ks[2][64 * 64];  // 2 x 8 KB: 64 keys x 64 d, swizzled
    __shared__ bf16 Vt[2][64 * 64];  // 2 x 8 KB: 64 d x 64 keys, swizzled
    __shared__ bf16 Ps[4][16 * 64];  //     8 KB: per-wave P [q][key], chunk-swizzled

    const int blk = blockIdx.x;
    const int ts = blk >> 5;                 // time-slot 0..31
    const int ta = ts >> 3, tb = ts & 7;
    int qt;
    if (ta == 0)      qt = tb;
    else if (ta == 1) qt = 31 - tb;
    else if (ta == 2) qt = 8 + tb;
    else              qt = 23 - tb;
    const int h = blk & 15;
    const int b = (blk >> 4) & 1;
    const int kvh = h >> 2;
    const int tid = threadIdx.x;
    const int w = tid >> 6, lane = tid & 63, g = lane >> 4, li = lane & 15;

    const bf16* qh = q + ((size_t)b * NH + h) * SS * HD;
    const bf16* kh = k + ((size_t)b * NKV + kvh) * SS * HD;
    const bf16* vh = vt + ((size_t)b * NKV + kvh) * (size_t)HD * SS;

    bf16x8 ones;
    #pragma unroll
    for (int jj = 0; jj < 8; ++jj) ones[jj] = (bf16)1.0f;
    const f32x4 z = {0.f, 0.f, 0.f, 0.f};

    // Q fragments straight from global (row=li, k=g*8+j); Q pre-scaled.
    const bf16* qrow = qh + (size_t)(qt * 64 + w * 16 + li) * HD;
    bf16x8 qf[2];
    qf[0] = *(const bf16x8*)(qrow + g * 8);
    qf[1] = *(const bf16x8*)(qrow + 32 + g * 8);

    // staging lane map (identical for K and V^T: 64-elem rows, 8 chunks, XOR swizzle)
    const int srow = tid >> 3;                           // 0..31 within 32-row sweep
    const int schunk = ((tid & 7) ^ (srow & 7)) * 8;
    const int lw = w * 512;

    const int xm = (li & 7) << 1;   // even Ps chunk-XOR mask (row-dependent, read==write)

    f32x4 o_acc[4], l_acc;
    #pragma unroll
    for (int nt = 0; nt < 4; ++nt) o_acc[nt] = z;
    l_acc = z;

    // ---- prologue: stage tiles 0 and 1 ----
    #pragma unroll
    for (int s = 0; s < 2; ++s)
        gl_lds16(kh + (size_t)(s * 32 + srow) * HD + schunk, &Ks[0][s * 2048 + lw]);
    #pragma unroll
    for (int s = 0; s < 2; ++s)
        gl_lds16(vh + (size_t)(s * 32 + srow) * SS + schunk, &Vt[0][s * 2048 + lw]);
    if (qt >= 1) {
        #pragma unroll
        for (int s = 0; s < 2; ++s)
            gl_lds16(kh + (size_t)(64 + s * 32 + srow) * HD + schunk, &Ks[1][s * 2048 + lw]);
        #pragma unroll
        for (int s = 0; s < 2; ++s)
            gl_lds16(vh + (size_t)(s * 32 + srow) * SS + 64 + schunk, &Vt[1][s * 2048 + lw]);
    }

    for (int kt = 0; kt <= qt; ++kt) {
        const int cur = kt & 1;
        if (kt < qt) { asm volatile("s_waitcnt vmcnt(4)" ::: "memory"); }
        else         { asm volatile("s_waitcnt vmcnt(0)" ::: "memory"); }
        __builtin_amdgcn_s_barrier();

        // S^T-fragment = K @ Q^T (swapped): lane (li,g) holds S[key=nt*16+g*4+r][q=li]
        f32x4 s_acc[4];
        #pragma unroll
        for (int nt = 0; nt < 4; ++nt) s_acc[nt] = z;
        __builtin_amdgcn_s_setprio(1);
        #pragma unroll
        for (int t = 0; t < 2; ++t)
            #pragma unroll
            for (int nt = 0; nt < 4; ++nt) {
                const bf16x8 kf = *(const bf16x8*)&Ks[cur][(nt * 16 + li) * 64 + (((t * 4 + g) ^ (li & 7)) * 8)];
                s_acc[nt] = __builtin_amdgcn_mfma_f32_16x16x32_bf16(kf, qf[t], s_acc[nt], 0, 0, 0);
            }
        __builtin_amdgcn_s_setprio(0);

        // exp2 + packed P -> LDS (bf16x4 per nt). Diag tile masked separately.
        if (kt == qt) {
            const int qrow_in = w * 16 + li;   // q within the 64-row q-tile
            #pragma unroll
            for (int nt = 0; nt < 4; ++nt) {
                bf16x4 p4;
                #pragma unroll
                for (int r = 0; r < 4; ++r) {
                    float sv = s_acc[nt][r];
                    if (nt * 16 + g * 4 + r > qrow_in) sv = -1e30f;
                    p4[r] = (bf16)exp2f(sv);
                }
                *(bf16x4*)&Ps[w][li * 64 + (((nt * 4 + g) ^ xm) * 4)] = p4;
            }
        } else {
            #pragma unroll
            for (int nt = 0; nt < 4; ++nt) {
                bf16x4 p4;
                #pragma unroll
                for (int r = 0; r < 4; ++r) p4[r] = (bf16)exp2f(s_acc[nt][r]);
                *(bf16x4*)&Ps[w][li * 64 + (((nt * 4 + g) ^ xm) * 4)] = p4;
            }
        }
        // same-wave LDS round-trip (rows are the lane's own q=li); no barrier needed

        // O += P @ V ; l += P @ 1 (rowsum via ones-MFMA)
        __builtin_amdgcn_s_setprio(1);
        #pragma unroll
        for (int t = 0; t < 2; ++t) {
            const bf16x8 pf = *(const bf16x8*)&Ps[w][li * 64 + (((t * 8 + g * 2) ^ xm) * 4)];
            l_acc = __builtin_amdgcn_mfma_f32_16x16x32_bf16(pf, ones, l_acc, 0, 0, 0);
            #pragma unroll
            for (int nt = 0; nt < 4; ++nt) {
                const bf16x8 vf = *(const bf16x8*)&Vt[cur][(nt * 16 + li) * 64 + (((t * 4 + g) ^ (li & 7)) * 8)];
                o_acc[nt] = __builtin_amdgcn_mfma_f32_16x16x32_bf16(pf, vf, o_acc[nt], 0, 0, 0);
            }
        }
        __builtin_amdgcn_s_setprio(0);

        __builtin_amdgcn_s_barrier();   // all waves done reading buf[cur]
        if (kt + 2 <= qt) {
            const size_t kq = (size_t)(kt + 2) * 64;
            #pragma unroll
            for (int s = 0; s < 2; ++s)
                gl_lds16(kh + (kq + s * 32 + srow) * HD + schunk, &Ks[cur][s * 2048 + lw]);
            #pragma unroll
            for (int s = 0; s < 2; ++s)
                gl_lds16(vh + (size_t)(s * 32 + srow) * SS + kq + schunk, &Vt[cur][s * 2048 + lw]);
        }
    }

    // epilogue: O / l -> (b, s, h, d) bf16
    #pragma unroll
    for (int r = 0; r < 4; ++r) {
        const float inv = 1.f / l_acc[r];
        const int s = qt * 64 + w * 16 + g * 4 + r;
        bf16* orow = o + (((size_t)b * SS + s) * NH + h) * HD;
        #pragma unroll
        for (int nt = 0; nt < 4; ++nt) orow[nt * 16 + li] = (bf16)(o_acc[nt][r] * inv);
    }
}

extern "C" void kernel_launch(void* const* d_in, const int* in_sizes, int n_in,
                              void* d_out, int out_size, void* d_ws, size_t ws_size,
                              hipStream_t stream) {
    const float* x     = (const float*)d_in[0];
    const float* cos_t = (const float*)d_in[1];
    const float* sin_t = (const float*)d_in[2];
    const float* Wq    = (const float*)d_in[3];
    const float* Wk    = (const float*)d_in[4];
    const float* Wv    = (const float*)d_in[5];
    const float* Wo    = (const float*)d_in[6];
    float* out = (float*)d_out;

    char* wsb = (char*)d_ws;
    bf16* o_b    = (bf16*)(wsb);                 //  8,388,608 B (attention output)
    bf16* wqkv_t = (bf16*)(wsb + 8388608);       //  3,145,728 B (1536 x 1024)
    bf16* wo_t   = (bf16*)(wsb + 11534336);      //  2,097,152 B (1024 x 1024)
    bf16* q_b    = (bf16*)(wsb + 13631488);      //  8,388,608 B
    bf16* k_b    = (bf16*)(wsb + 22020096);      //  2,097,152 B
    bf16* vt_b   = (bf16*)(wsb + 24117248);      //  2,097,152 B
    bf16* x_b    = (bf16*)(wsb + 26214400);      //  8,388,608 B -> total 34,603,008 B

    prep_kernel<<<896, 256, 0, stream>>>(x, Wq, Wk, Wv, Wo, wqkv_t, wo_t, x_b);

    // QKV GEMM: A = x_b (bf16), 64x128 tiles, BK=32 3-buf (36 KB -> 4 blocks/CU). Grid 768.
    gemm_qkv32_kernel<<<768, 256, 0, stream>>>(x_b, wqkv_t, cos_t, sin_t,
                                               q_b, k_b, vt_b, 1536, 1024, 12);
    flash_kernel<<<1024, 256, 0, stream>>>(q_b, k_b, vt_b, o_b);
    // O GEMM: 64x128 tiles, BK=64 3-buf single-barrier (72 KB; grid 512 caps at 2/CU anyway).
    gemm_o_kernel<<<512, 256, 0, stream>>>(o_b, wo_t, out, 1024, 1024, 8);
}

// Round 15
// 155.778 us; speedup vs baseline: 1.0554x; 1.0554x over previous
//
#include <hip/hip_runtime.h>

#define SS 2048
#define NH 16
#define NKV 4
#define HD 64

typedef __bf16 bf16;
typedef __bf16 bf16x4 __attribute__((ext_vector_type(4)));
typedef __bf16 bf16x8 __attribute__((ext_vector_type(8)));
typedef float f32x4 __attribute__((ext_vector_type(4)));

// softmax scale folded into Q at the QKV epilogue: (1/sqrt(64)) * log2(e)
#define SM_SCALE 0.18033688011f

__device__ __forceinline__ void gl_lds16(const bf16* g, bf16* l) {
    __builtin_amdgcn_global_load_lds((const __attribute__((address_space(1))) void*)g,
                                     (__attribute__((address_space(3))) void*)l, 16, 0, 0);
}

// ---------------- prep: transpose/convert weights + convert x to bf16 ----------------
__global__ __launch_bounds__(256) void prep_kernel(
    const float* __restrict__ x,
    const float* __restrict__ Wq, const float* __restrict__ Wk,
    const float* __restrict__ Wv, const float* __restrict__ Wo,
    bf16* __restrict__ wqkv_t, bf16* __restrict__ wo_t, bf16* __restrict__ xb)
{
    const int blk = blockIdx.x;
    const int tid = threadIdx.x;
    if (blk >= 640) {
        const size_t i0 = (size_t)(blk - 640) * 16384;
        #pragma unroll
        for (int i = 0; i < 16; ++i) {
            const size_t idx = i0 + i * 1024 + tid * 4;
            const float4 v = *(const float4*)&x[idx];
            bf16x4 o4;
            o4[0] = (bf16)v.x; o4[1] = (bf16)v.y; o4[2] = (bf16)v.z; o4[3] = (bf16)v.w;
            *(bf16x4*)&xb[idx] = o4;
        }
        return;
    }
    const float* W; bf16* Wt; int N, n0, k0;
    if (blk < 256)      { W = Wq; Wt = wqkv_t;                       N = 1024; n0 = (blk & 15) * 64;         k0 = (blk >> 4) * 64; }
    else if (blk < 320) { W = Wk; Wt = wqkv_t + (size_t)1024 * 1024; N = 256;  n0 = ((blk - 256) & 3) * 64;  k0 = ((blk - 256) >> 2) * 64; }
    else if (blk < 384) { W = Wv; Wt = wqkv_t + (size_t)1280 * 1024; N = 256;  n0 = ((blk - 320) & 3) * 64;  k0 = ((blk - 320) >> 2) * 64; }
    else                { W = Wo; Wt = wo_t;                         N = 1024; n0 = ((blk - 384) & 15) * 64; k0 = ((blk - 384) >> 4) * 64; }

    __shared__ float Ts[64][65];
    const int c = tid & 63, rr = tid >> 6;
    #pragma unroll
    for (int i = 0; i < 16; ++i) {
        const int kk = i * 4 + rr;
        Ts[kk][c] = W[(size_t)(k0 + kk) * N + n0 + c];
    }
    __syncthreads();
    #pragma unroll
    for (int i = 0; i < 16; ++i) {
        const int nn = i * 4 + rr;
        Wt[(size_t)(n0 + nn) * 1024 + k0 + c] = (bf16)Ts[c][nn];
    }
}

// ---------------- bf16 MFMA GEMM, 256 threads (4 waves), 64x128 tile, BK=64 ----------------
// NBUF=2 (best for 3-blocks/CU grids): counted-vmcnt double-buffer, 2 barriers:
//   iter t: s_waitcnt vmcnt(6); s_barrier; compute(buf[t&1]); s_barrier; stage(t+2).
// NBUF=3 (for grid-limited 2-blocks/CU kernels ONLY): single barrier + early stage issue.
// Tile/BK ledger: 128^2 @1.5/CU = 54us (grid-starved); 64x64 @5/CU regressed (staged
// bytes/output-elem); BK=32 @4/CU regressed (per-step fixed cost at 8 MFMA/step).
// 64x128 BK=64 @3/CU is the verified optimum.
// Unpadded LDS, chunk-XOR swizzle; XCD-locality mapping (rb spans within XCD).
// EPI=0: C fp32 plain. EPI=2: fused RoPE + QKV split epilogue, Q pre-scaled, packed V^T.
template<int EPI, int NBUF>
__global__ __launch_bounds__(256) void gemm_bt_kernel(
    const bf16* __restrict__ A, const bf16* __restrict__ Bt, float* __restrict__ C,
    const float* __restrict__ cosp, const float* __restrict__ sinp,
    bf16* __restrict__ qo, bf16* __restrict__ ko, bf16* __restrict__ vto,
    int N, int K, int CB)
{
    __shared__ bf16 As[NBUF][64 * 64];    // NBUF x  8 KB
    __shared__ bf16 Bs[NBUF][128 * 64];   // NBUF x 16 KB
    const int bid = blockIdx.x;
    const int j = bid >> 3;
    const int rb = (bid & 7) + 8 * (j / CB);
    const int cb = j % CB;
    const int m0 = rb * 64, n0 = cb * 128;
    const int tid = threadIdx.x;
    const int w = tid >> 6, lane = tid & 63, g = lane >> 4, li = lane & 15;
    const int wm = w >> 1, wn = w & 1;  // wave tile: rows wm*32+mi*16 (mi<2), cols wn*64+ni*16 (ni<4)

    f32x4 acc[2][4];
    const f32x4 z = {0.f, 0.f, 0.f, 0.f};
    #pragma unroll
    for (int i = 0; i < 2; ++i)
        #pragma unroll
        for (int jj = 0; jj < 4; ++jj) acc[i][jj] = z;

    // staging sweep = 256 thr x 16B = 32 rows x 64 elems; A: 2 sweeps, B: 4 sweeps.
    const int srow = tid >> 3;                          // 0..31 (row within sweep)
    const int schunk = ((tid & 7) ^ (srow & 7)) * 8;    // pre-swizzled global chunk
    const bf16* pA[2];
    const bf16* pB[4];
    #pragma unroll
    for (int s = 0; s < 2; ++s) pA[s] = A + (size_t)(m0 + s * 32 + srow) * K + schunk;
    #pragma unroll
    for (int s = 0; s < 4; ++s) pB[s] = Bt + (size_t)(n0 + s * 32 + srow) * K + schunk;
    const int lw = w * 512;   // wave-uniform LDS offset within each 2048-elem sweep region

    const int NT = K >> 6;    // 16 K-steps

    // ---- prologue: stage tiles 0 and 1 into buf 0 and 1 (6 gl_lds per thread per tile) ----
    #pragma unroll
    for (int s = 0; s < 2; ++s) gl_lds16(pA[s], &As[0][s * 2048 + lw]);
    #pragma unroll
    for (int s = 0; s < 4; ++s) gl_lds16(pB[s], &Bs[0][s * 2048 + lw]);
    #pragma unroll
    for (int s = 0; s < 2; ++s) gl_lds16(pA[s] + 64, &As[1][s * 2048 + lw]);
    #pragma unroll
    for (int s = 0; s < 4; ++s) gl_lds16(pB[s] + 64, &Bs[1][s * 2048 + lw]);

    if (NBUF == 2) {
        for (int t = 0; t < NT; ++t) {
            const int cur = t & 1;
            // wait for stage(t) only; stage(t+1)'s 6 loads stay in flight across the barrier
            if (t + 1 < NT) { asm volatile("s_waitcnt vmcnt(6)" ::: "memory"); }
            else            { asm volatile("s_waitcnt vmcnt(0)" ::: "memory"); }
            __builtin_amdgcn_s_barrier();
            #pragma unroll
            for (int tt = 0; tt < 2; ++tt) {
                const int phys = ((tt * 4 + g) ^ (li & 7)) * 8;
                bf16x8 af[2], bfr[4];
                #pragma unroll
                for (int mi = 0; mi < 2; ++mi) af[mi] = *(const bf16x8*)&As[cur][(wm * 32 + mi * 16 + li) * 64 + phys];
                #pragma unroll
                for (int ni = 0; ni < 4; ++ni) bfr[ni] = *(const bf16x8*)&Bs[cur][(wn * 64 + ni * 16 + li) * 64 + phys];
                __builtin_amdgcn_s_setprio(1);
                #pragma unroll
                for (int mi = 0; mi < 2; ++mi)
                    #pragma unroll
                    for (int ni = 0; ni < 4; ++ni)
                        acc[mi][ni] = __builtin_amdgcn_mfma_f32_16x16x32_bf16(af[mi], bfr[ni], acc[mi][ni], 0, 0, 0);
                __builtin_amdgcn_s_setprio(0);
            }
            __builtin_amdgcn_s_barrier();   // all waves done READING buf[cur] (no vmcnt drain)
            if (t + 2 < NT) {
                const int kk = (t + 2) << 6;
                #pragma unroll
                for (int s = 0; s < 2; ++s) gl_lds16(pA[s] + kk, &As[cur][s * 2048 + lw]);
                #pragma unroll
                for (int s = 0; s < 4; ++s) gl_lds16(pB[s] + kk, &Bs[cur][s * 2048 + lw]);
            }
        }
    } else {
        int cur = 0;
        for (int t = 0; t < NT; ++t) {
            if (t + 1 < NT) { asm volatile("s_waitcnt vmcnt(6)" ::: "memory"); }
            else            { asm volatile("s_waitcnt vmcnt(0)" ::: "memory"); }
            __builtin_amdgcn_s_barrier();
            // issue next+1 staging into the buffer whose reads finished at iter t-1
            if (t + 2 < NT) {
                const int kk = (t + 2) << 6;
                const int nb = (cur + 2 >= 3) ? cur - 1 : cur + 2;   // (cur+2)%3
                #pragma unroll
                for (int s = 0; s < 2; ++s) gl_lds16(pA[s] + kk, &As[nb][s * 2048 + lw]);
                #pragma unroll
                for (int s = 0; s < 4; ++s) gl_lds16(pB[s] + kk, &Bs[nb][s * 2048 + lw]);
            }
            #pragma unroll
            for (int tt = 0; tt < 2; ++tt) {
                const int phys = ((tt * 4 + g) ^ (li & 7)) * 8;
                bf16x8 af[2], bfr[4];
                #pragma unroll
                for (int mi = 0; mi < 2; ++mi) af[mi] = *(const bf16x8*)&As[cur][(wm * 32 + mi * 16 + li) * 64 + phys];
                #pragma unroll
                for (int ni = 0; ni < 4; ++ni) bfr[ni] = *(const bf16x8*)&Bs[cur][(wn * 64 + ni * 16 + li) * 64 + phys];
                __builtin_amdgcn_s_setprio(1);
                #pragma unroll
                for (int mi = 0; mi < 2; ++mi)
                    #pragma unroll
                    for (int ni = 0; ni < 4; ++ni)
                        acc[mi][ni] = __builtin_amdgcn_mfma_f32_16x16x32_bf16(af[mi], bfr[ni], acc[mi][ni], 0, 0, 0);
                __builtin_amdgcn_s_setprio(0);
            }
            cur = (cur + 1 == 3) ? 0 : cur + 1;
        }
    }

    const int row0 = m0 + wm * 32, col0 = n0 + wn * 64;
    if (EPI == 0) {
        #pragma unroll
        for (int mi = 0; mi < 2; ++mi)
            #pragma unroll
            for (int ni = 0; ni < 4; ++ni)
                #pragma unroll
                for (int r = 0; r < 4; ++r)
                    C[(size_t)(row0 + mi * 16 + g * 4 + r) * N + col0 + ni * 16 + li] = acc[mi][ni][r];
    } else {
        // fused RoPE + split. cols: [0,1024) q (pre-scaled), [1024,1280) k, [1280,1536) v.
        // rotate_half partner of col is col^32 == acc[mi][ni^2][r] (same wave, in-register).
        #pragma unroll
        for (int ni = 0; ni < 4; ++ni) {
            const int col = col0 + ni * 16 + li;
            const int d = col & 63;
            #pragma unroll
            for (int mi = 0; mi < 2; ++mi) {
                const int rowb = row0 + mi * 16 + g * 4;       // 4-aligned, never crosses b
                const int bb = rowb >> 11, s0 = rowb & 2047;
                if (col < 1280) {
                    #pragma unroll
                    for (int r = 0; r < 4; ++r) {
                        const int s = s0 + r;
                        float val = acc[mi][ni][r];
                        const float pairv = acc[mi][ni ^ 2][r];
                        const float rot = (d < 32) ? -pairv : pairv;
                        val = val * cosp[s * 64 + d] + rot * sinp[s * 64 + d];
                        if (col < 1024) {
                            const int hh = col >> 6;
                            qo[(((size_t)bb * NH + hh) * SS + s) * HD + d] = (bf16)(val * SM_SCALE);
                        } else {
                            const int kh = (col - 1024) >> 6;
                            ko[(((size_t)bb * NKV + kh) * SS + s) * HD + d] = (bf16)val;
                        }
                    }
                } else {
                    // V^T [d][s]: the 4 r-values are s-contiguous -> one 8B packed store
                    const int kh = (col - 1280) >> 6;
                    bf16x4 p4;
                    #pragma unroll
                    for (int r = 0; r < 4; ++r) p4[r] = (bf16)acc[mi][ni][r];
                    *(bf16x4*)&vto[(((size_t)bb * NKV + kh) * HD + d) * SS + s0] = p4;
                }
            }
        }
    }
}

// ---------------- Flash attention v12 (best measured): v9 loop + balanced qt permutation ----
// 1024 blocks x 256 thr, 4 blocks/CU all resident from t=0. Per-CU-balanced qt mapping
// (t = 8a+b): a=0: qt=b; a=1: qt=31-b; a=2: qt=8+b; a=3: qt=23-b — co-resident sets sum
// to 62 (uniform 66 tiles/CU). Structure ledger: QBLK=128 8-wave (r5,r7) and split-KV
// (r12) all regressed — v9's 4 small independent blocks/CU is the local optimum; kernel
// is VALU+MFMA co-bound (54% VALU + 17% MFMA overlapped across waves).
// Inner loop: counted-vmcnt dbuf KVBLK=64, swapped QK^T (lane holds
// S[key=nt*16+g*4+r][q=li]), packed bf16x4 P writes, chunk-XOR swizzled LDS.
__global__ __launch_bounds__(256) void flash_kernel(const bf16* __restrict__ q, const bf16* __restrict__ k,
                                                    const bf16* __restrict__ vt, bf16* __restrict__ o)
{
    __shared__ bf16 Ks[2][64 * 64];  // 2 x 8 KB: 64 keys x 64 d, swizzled
    __shared__ bf16 Vt[2][64 * 64];  // 2 x 8 KB: 64 d x 64 keys, swizzled
    __shared__ bf16 Ps[4][16 * 64];  //     8 KB: per-wave P [q][key], chunk-swizzled

    const int blk = blockIdx.x;
    const int ts = blk >> 5;                 // time-slot 0..31
    const int ta = ts >> 3, tb = ts & 7;
    int qt;
    if (ta == 0)      qt = tb;
    else if (ta == 1) qt = 31 - tb;
    else if (ta == 2) qt = 8 + tb;
    else              qt = 23 - tb;
    const int h = blk & 15;
    const int b = (blk >> 4) & 1;
    const int kvh = h >> 2;
    const int tid = threadIdx.x;
    const int w = tid >> 6, lane = tid & 63, g = lane >> 4, li = lane & 15;

    const bf16* qh = q + ((size_t)b * NH + h) * SS * HD;
    const bf16* kh = k + ((size_t)b * NKV + kvh) * SS * HD;
    const bf16* vh = vt + ((size_t)b * NKV + kvh) * (size_t)HD * SS;

    bf16x8 ones;
    #pragma unroll
    for (int jj = 0; jj < 8; ++jj) ones[jj] = (bf16)1.0f;
    const f32x4 z = {0.f, 0.f, 0.f, 0.f};

    // Q fragments straight from global (row=li, k=g*8+j); Q pre-scaled.
    const bf16* qrow = qh + (size_t)(qt * 64 + w * 16 + li) * HD;
    bf16x8 qf[2];
    qf[0] = *(const bf16x8*)(qrow + g * 8);
    qf[1] = *(const bf16x8*)(qrow + 32 + g * 8);

    // staging lane map (identical for K and V^T: 64-elem rows, 8 chunks, XOR swizzle)
    const int srow = tid >> 3;                           // 0..31 within 32-row sweep
    const int schunk = ((tid & 7) ^ (srow & 7)) * 8;
    const int lw = w * 512;

    const int xm = (li & 7) << 1;   // even Ps chunk-XOR mask (row-dependent, read==write)

    f32x4 o_acc[4], l_acc;
    #pragma unroll
    for (int nt = 0; nt < 4; ++nt) o_acc[nt] = z;
    l_acc = z;

    // ---- prologue: stage tiles 0 and 1 ----
    #pragma unroll
    for (int s = 0; s < 2; ++s)
        gl_lds16(kh + (size_t)(s * 32 + srow) * HD + schunk, &Ks[0][s * 2048 + lw]);
    #pragma unroll
    for (int s = 0; s < 2; ++s)
        gl_lds16(vh + (size_t)(s * 32 + srow) * SS + schunk, &Vt[0][s * 2048 + lw]);
    if (qt >= 1) {
        #pragma unroll
        for (int s = 0; s < 2; ++s)
            gl_lds16(kh + (size_t)(64 + s * 32 + srow) * HD + schunk, &Ks[1][s * 2048 + lw]);
        #pragma unroll
        for (int s = 0; s < 2; ++s)
            gl_lds16(vh + (size_t)(s * 32 + srow) * SS + 64 + schunk, &Vt[1][s * 2048 + lw]);
    }

    for (int kt = 0; kt <= qt; ++kt) {
        const int cur = kt & 1;
        if (kt < qt) { asm volatile("s_waitcnt vmcnt(4)" ::: "memory"); }
        else         { asm volatile("s_waitcnt vmcnt(0)" ::: "memory"); }
        __builtin_amdgcn_s_barrier();

        // S^T-fragment = K @ Q^T (swapped): lane (li,g) holds S[key=nt*16+g*4+r][q=li]
        f32x4 s_acc[4];
        #pragma unroll
        for (int nt = 0; nt < 4; ++nt) s_acc[nt] = z;
        __builtin_amdgcn_s_setprio(1);
        #pragma unroll
        for (int t = 0; t < 2; ++t)
            #pragma unroll
            for (int nt = 0; nt < 4; ++nt) {
                const bf16x8 kf = *(const bf16x8*)&Ks[cur][(nt * 16 + li) * 64 + (((t * 4 + g) ^ (li & 7)) * 8)];
                s_acc[nt] = __builtin_amdgcn_mfma_f32_16x16x32_bf16(kf, qf[t], s_acc[nt], 0, 0, 0);
            }
        __builtin_amdgcn_s_setprio(0);

        // exp2 + packed P -> LDS (bf16x4 per nt). Diag tile masked separately.
        if (kt == qt) {
            const int qrow_in = w * 16 + li;   // q within the 64-row q-tile
            #pragma unroll
            for (int nt = 0; nt < 4; ++nt) {
                bf16x4 p4;
                #pragma unroll
                for (int r = 0; r < 4; ++r) {
                    float sv = s_acc[nt][r];
                    if (nt * 16 + g * 4 + r > qrow_in) sv = -1e30f;
                    p4[r] = (bf16)exp2f(sv);
                }
                *(bf16x4*)&Ps[w][li * 64 + (((nt * 4 + g) ^ xm) * 4)] = p4;
            }
        } else {
            #pragma unroll
            for (int nt = 0; nt < 4; ++nt) {
                bf16x4 p4;
                #pragma unroll
                for (int r = 0; r < 4; ++r) p4[r] = (bf16)exp2f(s_acc[nt][r]);
                *(bf16x4*)&Ps[w][li * 64 + (((nt * 4 + g) ^ xm) * 4)] = p4;
            }
        }
        // same-wave LDS round-trip (rows are the lane's own q=li); no barrier needed

        // O += P @ V ; l += P @ 1 (rowsum via ones-MFMA)
        __builtin_amdgcn_s_setprio(1);
        #pragma unroll
        for (int t = 0; t < 2; ++t) {
            const bf16x8 pf = *(const bf16x8*)&Ps[w][li * 64 + (((t * 8 + g * 2) ^ xm) * 4)];
            l_acc = __builtin_amdgcn_mfma_f32_16x16x32_bf16(pf, ones, l_acc, 0, 0, 0);
            #pragma unroll
            for (int nt = 0; nt < 4; ++nt) {
                const bf16x8 vf = *(const bf16x8*)&Vt[cur][(nt * 16 + li) * 64 + (((t * 4 + g) ^ (li & 7)) * 8)];
                o_acc[nt] = __builtin_amdgcn_mfma_f32_16x16x32_bf16(pf, vf, o_acc[nt], 0, 0, 0);
            }
        }
        __builtin_amdgcn_s_setprio(0);

        __builtin_amdgcn_s_barrier();   // all waves done reading buf[cur]
        if (kt + 2 <= qt) {
            const size_t kq = (size_t)(kt + 2) * 64;
            #pragma unroll
            for (int s = 0; s < 2; ++s)
                gl_lds16(kh + (kq + s * 32 + srow) * HD + schunk, &Ks[cur][s * 2048 + lw]);
            #pragma unroll
            for (int s = 0; s < 2; ++s)
                gl_lds16(vh + (size_t)(s * 32 + srow) * SS + kq + schunk, &Vt[cur][s * 2048 + lw]);
        }
    }

    // epilogue: O / l -> (b, s, h, d) bf16
    #pragma unroll
    for (int r = 0; r < 4; ++r) {
        const float inv = 1.f / l_acc[r];
        const int s = qt * 64 + w * 16 + g * 4 + r;
        bf16* orow = o + (((size_t)b * SS + s) * NH + h) * HD;
        #pragma unroll
        for (int nt = 0; nt < 4; ++nt) orow[nt * 16 + li] = (bf16)(o_acc[nt][r] * inv);
    }
}

extern "C" void kernel_launch(void* const* d_in, const int* in_sizes, int n_in,
                              void* d_out, int out_size, void* d_ws, size_t ws_size,
                              hipStream_t stream) {
    const float* x     = (const float*)d_in[0];
    const float* cos_t = (const float*)d_in[1];
    const float* sin_t = (const float*)d_in[2];
    const float* Wq    = (const float*)d_in[3];
    const float* Wk    = (const float*)d_in[4];
    const float* Wv    = (const float*)d_in[5];
    const float* Wo    = (const float*)d_in[6];
    float* out = (float*)d_out;

    char* wsb = (char*)d_ws;
    bf16* o_b    = (bf16*)(wsb);                 //  8,388,608 B (attention output)
    bf16* wqkv_t = (bf16*)(wsb + 8388608);       //  3,145,728 B (1536 x 1024)
    bf16* wo_t   = (bf16*)(wsb + 11534336);      //  2,097,152 B (1024 x 1024)
    bf16* q_b    = (bf16*)(wsb + 13631488);      //  8,388,608 B
    bf16* k_b    = (bf16*)(wsb + 22020096);      //  2,097,152 B
    bf16* vt_b   = (bf16*)(wsb + 24117248);      //  2,097,152 B
    bf16* x_b    = (bf16*)(wsb + 26214400);      //  8,388,608 B -> total 34,603,008 B

    prep_kernel<<<896, 256, 0, stream>>>(x, Wq, Wk, Wv, Wo, wqkv_t, wo_t, x_b);

    // QKV GEMM: A = x_b (bf16), 64x128 tiles, 2-buf (48 KB -> 3 blocks/CU). Grid 768.
    gemm_bt_kernel<2, 2><<<768, 256, 0, stream>>>(x_b, wqkv_t, nullptr, cos_t, sin_t,
                                                  q_b, k_b, vt_b, 1536, 1024, 12);
    flash_kernel<<<1024, 256, 0, stream>>>(q_b, k_b, vt_b, o_b);
    // O GEMM: 64x128 tiles, 3-buf single-barrier (72 KB; grid 512 caps at 2 blocks/CU anyway).
    gemm_bt_kernel<0, 3><<<512, 256, 0, stream>>>(o_b, wo_t, out, nullptr, nullptr,
                                                  nullptr, nullptr, nullptr, 1024, 1024, 8);
}